// Round 8
// baseline (1220.243 us; speedup 1.0000x reference)
//
#include <hip/hip_runtime.h>
#include <hip/hip_bf16.h>
#include <cstdint>
#include <cstddef>

typedef __bf16 bf16_t;
typedef __bf16 bf16x4 __attribute__((ext_vector_type(4)));
typedef __bf16 bf16x8 __attribute__((ext_vector_type(8)));
typedef float  f32x4  __attribute__((ext_vector_type(4)));

#define L_DIM 2048
#define N_DIM 8
#define E_DIM 2048
#define H_DIM 8192
#define T_DIM (L_DIM * N_DIM)   // 16384 tokens

// ---------------------------------------------------------------------------
__global__ __launch_bounds__(256) void cvt_f32_bf16(const float* __restrict__ in,
                                                    bf16_t* __restrict__ out,
                                                    int n4) {
    int stride = gridDim.x * blockDim.x;
    for (int i = blockIdx.x * blockDim.x + threadIdx.x; i < n4; i += stride) {
        float4 v = *(const float4*)(in + (size_t)i * 4);
        bf16x4 o;
        o[0] = (bf16_t)v.x; o[1] = (bf16_t)v.y;
        o[2] = (bf16_t)v.z; o[3] = (bf16_t)v.w;
        *(bf16x4*)(out + (size_t)i * 4) = o;
    }
}

// ---------------------------------------------------------------------------
__device__ __forceinline__ float fast_gelu(float x) {
    float x2 = x * x;
    float w  = x * __builtin_fmaf(0.1029456f, x2, 2.3022618f);
    w = fminf(w, 60.0f);
    float s = __builtin_amdgcn_exp2f(w);
    float r = __builtin_amdgcn_rcpf(s + 1.0f);
    return x * s * r;
}

// ---------------------------------------------------------------------------
// Persistent 256x256 GEMM, READ-AHEAD pipelined phases:
// phase p issues ds_reads for phase p+1's fragments (double-buffered regs:
// afX/afY alternate per phase; B of next K-iter read at ph2 into off-iter
// set), then MFMAs on fragments read at phase p-1 -> LDS pipe (~2300 cyc/
// K-iter) hides under MFMA pipe (~2480 cyc). ONE barrier per phase;
// uniform vmcnt(6) per phase-end guarantees the half-tile staged 4 phases
// ago has landed before its first reader (stage schedule unchanged:
// A1(t+1)@ph0, B0(t+2)@ph1, B1(t+2)@ph2, A0(t+2)@ph3).
// Read schedule: ph0->A23(t), ph1->A45(t), ph2->A67(t)+B(t+1), ph3->A01(t+1).
// lgkmcnt before MFMA = reads issued this phase (4,4,12,12).
// Staging layout / LDS swizzle / XCD swizzle / epilogue identical to R7.
// ---------------------------------------------------------------------------
template <bool GELU_OUT, int LG_NT, int LG_TN, int LG_NTILE, int KDIM, int NDIM>
__global__ __launch_bounds__(512, 2) void gemm256(const bf16_t* __restrict__ Am,
                                                  const bf16_t* __restrict__ Bm,
                                                  const float* __restrict__ bias,
                                                  void* __restrict__ Cout) {
    extern __shared__ char lds[];
    constexpr int NT    = 1 << LG_NT;
    constexpr int ntile = 1 << LG_NTILE;

    const int tid  = threadIdx.x;
    const int lane = tid & 63;
    const int wid  = tid >> 6;
    const int wr   = wid >> 2;
    const int wc   = wid & 3;

    const int wgb = (blockIdx.x & 7) * 32 + (blockIdx.x >> 3);
    const int g0  = wgb << LG_NTILE;

    // staging lane geometry (pre-swizzled source, linear LDS dest)
    const int srow    = wid * 8 + (lane >> 3);
    const int scol8   = ((lane & 7) ^ (lane >> 3)) * 8;
    const int laneOff = srow * KDIM + scol8;

    // hoisted LDS read bases: {A,B} x {kk} x {parity}
    const int l15 = lane & 15;
    const int sl0 = ((lane >> 4)    ) ^ (lane & 7);
    const int sl1 = (4 + (lane >> 4)) ^ (lane & 7);
    const unsigned rdA0_0 = (unsigned)((wr * 32 + l15) * 128 + sl0 * 16);
    const unsigned rdA1_0 = (unsigned)((wr * 32 + l15) * 128 + sl1 * 16);
    const unsigned rdB0_0 = (unsigned)(32768 + (wc * 64 + l15) * 128 + sl0 * 16);
    const unsigned rdB1_0 = (unsigned)(32768 + (wc * 64 + l15) * 128 + sl1 * 16);
    const unsigned rdA0_1 = rdA0_0 + 65536u;
    const unsigned rdA1_1 = rdA1_0 + 65536u;
    const unsigned rdB0_1 = rdB0_0 + 65536u;
    const unsigned rdB1_1 = rdB1_0 + 65536u;

// P,M,N,KK are compile-time literals -> base select + imm offset fold.
#define LDA(P, M, KK) (*(const bf16x8*)(lds + ((KK) ? ((P) ? rdA1_1 : rdA1_0)      \
                                                    : ((P) ? rdA0_1 : rdA0_0))      \
                                            + ((M) >> 1) * 8192 + ((M) & 1) * 2048))
#define LDB(P, N, KK) (*(const bf16x8*)(lds + ((KK) ? ((P) ? rdB1_1 : rdB1_0)      \
                                                    : ((P) ? rdB0_1 : rdB0_0))      \
                                            + (N) * 2048))
#define RD_A(dst, P, M0) do {                                                       \
        dst[0][0] = LDA(P, (M0),     0); dst[0][1] = LDA(P, (M0),     1);           \
        dst[1][0] = LDA(P, (M0) + 1, 0); dst[1][1] = LDA(P, (M0) + 1, 1); } while (0)
#define RD_B(dst, P) do {                                                           \
        dst[0][0] = LDB(P, 0, 0); dst[0][1] = LDB(P, 0, 1);                         \
        dst[1][0] = LDB(P, 1, 0); dst[1][1] = LDB(P, 1, 1);                         \
        dst[2][0] = LDB(P, 2, 0); dst[2][1] = LDB(P, 2, 1);                         \
        dst[3][0] = LDB(P, 3, 0); dst[3][1] = LDB(P, 3, 1); } while (0)

#define GLL(src, dofs)                                                              \
    __builtin_amdgcn_global_load_lds(                                               \
        (const __attribute__((address_space(1))) void*)(src),                       \
        (__attribute__((address_space(3))) void*)(lds + (dofs)), 16, 0, 0)

#define STAGE(BASE, ISB, HALF, PARL, KT) do {                                       \
        const bf16_t* s0_ = (BASE) + (size_t)(HALF) * 128 * KDIM + laneOff          \
                          + ((KT) << 6);                                            \
        const unsigned d_ = ((unsigned)((PARL) << 16) | ((unsigned)(ISB) << 15)     \
                          | ((unsigned)(HALF) << 14)) | ((unsigned)wid << 10);      \
        GLL(s0_, d_);                                                               \
        GLL(s0_ + (size_t)64 * KDIM, d_ + 8192); } while (0)

#define MFMA16(AB, AF, BF) do {                                                     \
        _Pragma("unroll") for (int mm = 0; mm < 2; ++mm)                            \
        _Pragma("unroll") for (int n = 0; n < 4; ++n)                               \
        _Pragma("unroll") for (int kk = 0; kk < 2; ++kk)                            \
            acc[(AB) + mm][n] = __builtin_amdgcn_mfma_f32_16x16x32_bf16(            \
                AF[mm][kk], BF[n][kk], acc[(AB) + mm][n], 0, 0, 0); } while (0)

#define PH_MID(LGKM)                                                                \
        __builtin_amdgcn_sched_barrier(0);                                          \
        asm volatile("s_waitcnt lgkmcnt(" #LGKM ")" ::: "memory");                  \
        __builtin_amdgcn_sched_barrier(0);                                          \
        __builtin_amdgcn_s_setprio(1);
#define PH_END                                                                      \
        __builtin_amdgcn_s_setprio(0);                                              \
        asm volatile("s_waitcnt vmcnt(6)" ::: "memory");                            \
        __builtin_amdgcn_s_barrier();

// One K-iteration (BK=64). BC = B regs for iter t, BN = B regs for t+1.
// PAR = t&1 (literal). MFMA(ph p) uses frags read at p-1.
#define KITER(T_, BC, BN, PAR) do {                                                 \
        const int t_  = (T_);                                                       \
        const int kt1 = (t_ + 1) & (NT - 1);                                        \
        const int kt2 = (t_ + 2) & (NT - 1);                                        \
        const bool nx1 = (t_ == NT - 1);                                            \
        const bool nx2 = (t_ >= NT - 2);                                            \
        /* ph0: read A23(t); stage A1(t+1); MFMA m01 on afX */                      \
        RD_A(afY, PAR, 2);                                                          \
        STAGE(nx1 ? aNxt : aCur, 0, 1, (PAR) ^ 1, kt1);                             \
        PH_MID(4)  MFMA16(0, afX, BC); PH_END                                       \
        /* ph1: read A45(t); stage B0(t+2); MFMA m23 on afY */                      \
        RD_A(afX, PAR, 4);                                                          \
        STAGE(nx2 ? bNxt : bCur, 1, 0, PAR, kt2);                                   \
        PH_MID(4)  MFMA16(2, afY, BC); PH_END                                       \
        /* ph2: read A67(t) + B(t+1); stage B1(t+2); MFMA m45 on afX */             \
        RD_A(afY, PAR, 6);                                                          \
        RD_B(BN, (PAR) ^ 1);                                                        \
        STAGE(nx2 ? bNxt : bCur, 1, 1, PAR, kt2);                                   \
        PH_MID(12) MFMA16(4, afX, BC); PH_END                                       \
        /* ph3: read A01(t+1); stage A0(t+2); MFMA m67 on afY */                    \
        RD_A(afX, (PAR) ^ 1, 0);                                                    \
        STAGE(nx2 ? aNxt : aCur, 0, 0, PAR, kt2);                                   \
        PH_MID(12) MFMA16(6, afY, BC); PH_END                                       \
    } while (0)

    // tile base pointers (wave-uniform -> SGPR)
    const bf16_t* aCur = Am + ((size_t)(g0 >> LG_TN) << 8) * KDIM;
    const bf16_t* bCur = Bm + ((size_t)(g0 & ((1 << LG_TN) - 1)) << 8) * KDIM;
    const bf16_t* aNxt = aCur;
    const bf16_t* bNxt = bCur;

    f32x4  acc[8][4] = {};
    bf16x8 bfA[4][2], bfB[4][2], afX[2][2], afY[2][2];

    // Prologue: stages in steady-state order (B0,B1,A0,A1 slot0; B0,B1,A0 slot1)
    STAGE(bCur, 1, 0, 0, 0); STAGE(bCur, 1, 1, 0, 0);
    STAGE(aCur, 0, 0, 0, 0); STAGE(aCur, 0, 1, 0, 0);
    STAGE(bCur, 1, 0, 1, 1); STAGE(bCur, 1, 1, 1, 1);
    STAGE(aCur, 0, 0, 1, 1);
    asm volatile("s_waitcnt vmcnt(6)" ::: "memory");   // slot 0 landed
    __builtin_amdgcn_s_barrier();
    // pre-reads for iter 0 ph0: B(0) and A01(0)
    RD_B(bfA, 0);
    RD_A(afX, 0, 0);

    for (int ti = 0; ti < ntile; ++ti) {
        const int gn = (ti < ntile - 1) ? (g0 + ti + 1) : (g0 + ntile - 1);
        aNxt = Am + ((size_t)(gn >> LG_TN) << 8) * KDIM;
        bNxt = Bm + ((size_t)(gn & ((1 << LG_TN) - 1)) << 8) * KDIM;

        for (int t = 0; t < NT; t += 2) {
            KITER(t,     bfA, bfB, 0);
            KITER(t + 1, bfB, bfA, 1);
        }

        // ---- per-tile epilogue (reg-only; between ph3-barrier and next ph0) ----
        const int g = g0 + ti;
        const size_t rowBase = (size_t)(g >> LG_TN) << 8;
        const size_t colBase = (size_t)(g & ((1 << LG_TN) - 1)) << 8;
        const int orow = (lane >> 4) * 4;
        const int ocol = lane & 15;
#pragma unroll
        for (int m = 0; m < 8; ++m) {
            const size_t rb = rowBase + (size_t)((m >> 1) * 64 + wr * 32 + (m & 1) * 16 + orow);
#pragma unroll
            for (int n = 0; n < 4; ++n) {
                const size_t col = colBase + (size_t)(wc * 64 + n * 16 + ocol);
                const float bv = bias[col];
#pragma unroll
                for (int j = 0; j < 4; ++j) {
                    float v = acc[m][n][j] + bv;
                    if constexpr (GELU_OUT) {
                        ((bf16_t*)Cout)[(rb + j) * (size_t)NDIM + col] = (bf16_t)fast_gelu(v);
                    } else {
                        ((float*)Cout)[(rb + j) * (size_t)NDIM + col] = v;
                    }
                }
                acc[m][n] = (f32x4){0.f, 0.f, 0.f, 0.f};
            }
        }

        aCur = aNxt; bCur = bNxt;
    }
    asm volatile("s_waitcnt vmcnt(0)" ::: "memory");   // drain tail dummy loads

#undef KITER
#undef PH_END
#undef PH_MID
#undef MFMA16
#undef STAGE
#undef GLL
#undef RD_B
#undef RD_A
#undef LDB
#undef LDA
}

// ---------------------------------------------------------------------------
extern "C" void kernel_launch(void* const* d_in, const int* in_sizes, int n_in,
                              void* d_out, int out_size, void* d_ws, size_t ws_size,
                              hipStream_t stream) {
    const float* x  = (const float*)d_in[0];  // [16384, 2048]
    const float* p1 = (const float*)d_in[1];  // [8192, 2048]
    const float* b1 = (const float*)d_in[2];  // [8192]
    const float* p2 = (const float*)d_in[3];  // [2048, 8192]
    const float* b2 = (const float*)d_in[4];  // [2048]
    // d_in[5] = gate_w, unused (routing is identity on the output)
    float* out = (float*)d_out;

    char* ws = (char*)d_ws;
    bf16_t* xb  = (bf16_t*)(ws);                          // 64 MB
    bf16_t* p1b = (bf16_t*)(ws + ((size_t)64 << 20));     // 32 MB
    bf16_t* p2b = (bf16_t*)(ws + ((size_t)96 << 20));     // 32 MB
    bf16_t* h   = (bf16_t*)(ws + ((size_t)128 << 20));    // 256 MB

    // GEMM1: [T,E] x [H,E]^T -> h.  2048 tiles = 256 blocks x 8 tiles.
    auto g1 = gemm256<true, 5, 5, 3, E_DIM, H_DIM>;
    // GEMM2: [T,H] x [E,H]^T -> out. 512 tiles = 256 blocks x 2 tiles.
    auto g2 = gemm256<false, 7, 3, 1, H_DIM, E_DIM>;

    (void)hipFuncSetAttribute((const void*)g1,
                              hipFuncAttributeMaxDynamicSharedMemorySize, 131072);
    (void)hipFuncSetAttribute((const void*)g2,
                              hipFuncAttributeMaxDynamicSharedMemorySize, 131072);

    cvt_f32_bf16<<<2048, 256, 0, stream>>>(x,  xb,  (T_DIM * E_DIM) / 4);
    cvt_f32_bf16<<<1024, 256, 0, stream>>>(p1, p1b, (H_DIM * E_DIM) / 4);
    cvt_f32_bf16<<<1024, 256, 0, stream>>>(p2, p2b, (E_DIM * H_DIM) / 4);

    g1<<<256, 512, 131072, stream>>>(xb, p1b, b1, (void*)h);
    g2<<<256, 512, 131072, stream>>>(h, p2b, b2, (void*)out);
}

// Round 9
// 1019.438 us; speedup vs baseline: 1.1970x; 1.1970x over previous
//
#include <hip/hip_runtime.h>
#include <hip/hip_bf16.h>
#include <cstdint>
#include <cstddef>

typedef __bf16 bf16_t;
typedef __bf16 bf16x4 __attribute__((ext_vector_type(4)));
typedef __bf16 bf16x8 __attribute__((ext_vector_type(8)));
typedef float  f32x4  __attribute__((ext_vector_type(4)));

#define L_DIM 2048
#define N_DIM 8
#define E_DIM 2048
#define H_DIM 8192
#define T_DIM (L_DIM * N_DIM)   // 16384 tokens

// ---------------------------------------------------------------------------
__global__ __launch_bounds__(256) void cvt_f32_bf16(const float* __restrict__ in,
                                                    bf16_t* __restrict__ out,
                                                    int n4) {
    int stride = gridDim.x * blockDim.x;
    for (int i = blockIdx.x * blockDim.x + threadIdx.x; i < n4; i += stride) {
        float4 v = *(const float4*)(in + (size_t)i * 4);
        bf16x4 o;
        o[0] = (bf16_t)v.x; o[1] = (bf16_t)v.y;
        o[2] = (bf16_t)v.z; o[3] = (bf16_t)v.w;
        *(bf16x4*)(out + (size_t)i * 4) = o;
    }
}

// ---------------------------------------------------------------------------
__device__ __forceinline__ float fast_gelu(float x) {
    float x2 = x * x;
    float w  = x * __builtin_fmaf(0.1029456f, x2, 2.3022618f);
    w = fminf(w, 60.0f);
    float s = __builtin_amdgcn_exp2f(w);
    float r = __builtin_amdgcn_rcpf(s + 1.0f);
    return x * s * r;
}

// ---------------------------------------------------------------------------
// Persistent 256x256 GEMM, 4-barrier K-iter (overlapped phases).
// R6 base (data path identical) with the sync schedule restructured:
//   - stage ONLY slot u+1 during iter u (B0@ph0, B1@ph1, A0@ph2, A1@ph3)
//     -> all staging writes target the OPPOSITE LDS parity from all reads
//     -> any <1-phase wave skew is WAR-free, so the post-MFMA barriers can
//        be dropped: each phase is [stage; reads; (vmcnt); BAR; lgkm0; MFMA].
//     MFMA(p) and reads(p+1) now share a barrier-free region: the MFMA pipe
//     serializes the 2 waves/SIMD, staggering them so one wave's ds_reads
//     overlap the other's MFMA (the 2312-cyc LDS pipe hides under the
//     2483-cyc MFMA pipe instead of adding to it).
//   - counted vmcnt derivation (issue order B0,B1,A0,A1, 2 loads each):
//     vmcnt(4) @ph1-end: A1(u) [staged ph3(u-1)] landed before ph2 reads;
//     vmcnt(2) @ph3-end: B0,B1,A0(u+1) landed before ph0(u+1) reads; the
//     barrier right after each vmcnt publishes the drain to all waves.
//   Deadlines: B halves 3-4 phases, A0 2 phases, A1 3 phases. Dummy tail
//   stages (slot U) clamp to the last tile's address, land in the dead
//   parity buffer.
// ---------------------------------------------------------------------------
template <bool GELU_OUT, int LG_NT, int LG_TN, int LG_NTILE, int KDIM, int NDIM>
__global__ __launch_bounds__(512, 2) void gemm256(const bf16_t* __restrict__ Am,
                                                  const bf16_t* __restrict__ Bm,
                                                  const float* __restrict__ bias,
                                                  void* __restrict__ Cout) {
    extern __shared__ char lds[];
    constexpr int NT    = 1 << LG_NT;      // K-tiles per output tile (KDIM/64)
    constexpr int ntile = 1 << LG_NTILE;   // output tiles per block
    constexpr int U     = ntile << LG_NT;  // total flat K-iterations

    const int tid  = threadIdx.x;
    const int lane = tid & 63;
    const int wid  = tid >> 6;
    const int wr   = wid >> 2;   // 0..1
    const int wc   = wid & 3;    // 0..3

    // XCD-aware bijective swizzle over the fixed 256-block grid (q = 32)
    const int wgb = (blockIdx.x & 7) * 32 + (blockIdx.x >> 3);
    const int g0  = wgb << LG_NTILE;

    // staging lane geometry: row_in_half = wid*8 + (lane>>3), phys slot = lane&7,
    // pre-swizzled logical col slot = (lane&7) ^ (row&7)  [row&7 == lane>>3]
    const int srow  = wid * 8 + (lane >> 3);
    const int scol8 = ((lane & 7) ^ (lane >> 3)) * 8;

    auto STAGE = [&](int isB, int half, int slot) {
        const int us  = (slot < U) ? slot : (U - 1);       // clamp tail (dummy)
        const int ti_ = us >> LG_NT;
        const int kt_ = us & (NT - 1);
        const int g_  = g0 + ti_;
        const size_t base_ = (size_t)(isB ? (g_ & ((1 << LG_TN) - 1)) : (g_ >> LG_TN)) << 8;
        // parity from UNCLAMPED slot -> dummies land in the dead buffer
        const unsigned reg_ = (unsigned)(((slot & 1) << 16) | (isB << 15) | (half << 14));
        const bf16_t* s0 = (isB ? Bm : Am)
                         + (base_ + (size_t)(half * 128 + srow)) * (size_t)KDIM
                         + (size_t)((kt_ << 6) + scol8);
        __builtin_amdgcn_global_load_lds(
            (const __attribute__((address_space(1))) void*)s0,
            (__attribute__((address_space(3))) void*)(lds + reg_ + (unsigned)(wid * 1024)),
            16, 0, 0);
        __builtin_amdgcn_global_load_lds(
            (const __attribute__((address_space(1))) void*)(s0 + (size_t)64 * KDIM),
            (__attribute__((address_space(3))) void*)(lds + reg_ + (unsigned)((8 + wid) * 1024)),
            16, 0, 0);
    };

    // M-frag m of wave wr -> tile row (m>>1)*64 + wr*32 + (m&1)*16
    auto ldsA = [&](unsigned bufo, int m, int kk) -> bf16x8 {
        const int row  = (m >> 1) * 64 + wr * 32 + (m & 1) * 16 + (lane & 15);
        const int slot = ((kk << 2) + (lane >> 4)) ^ (lane & 7);
        return *(const bf16x8*)(lds + bufo + row * 128 + slot * 16);
    };
    auto ldsB = [&](unsigned bufo, int n, int kk) -> bf16x8 {
        const int row  = wc * 64 + n * 16 + (lane & 15);
        const int slot = ((kk << 2) + (lane >> 4)) ^ (lane & 7);
        return *(const bf16x8*)(lds + bufo + 32768 + row * 128 + slot * 16);
    };

    f32x4 acc[8][4] = {};

    // Prologue: stage slot 0 completely, drain, publish.
    STAGE(1, 0, 0); STAGE(1, 1, 0); STAGE(0, 0, 0); STAGE(0, 1, 0);
    asm volatile("s_waitcnt vmcnt(0)" ::: "memory");
    __builtin_amdgcn_s_barrier();

    for (int ti = 0; ti < ntile; ++ti) {
        for (int t = 0; t < NT; ++t) {
            const int u = (ti << LG_NT) + t;
            const unsigned cur = (unsigned)(t & 1) * 65536u;   // == (u&1), NT even
            bf16x8 bf[4][2];
            bf16x8 af[2][2];

            // ---- ph0: stage B0(u+1); read all B (8) + A m01 (4); MFMA m01 ----
            STAGE(1, 0, u + 1);
#pragma unroll
            for (int n = 0; n < 4; ++n)
#pragma unroll
                for (int kk = 0; kk < 2; ++kk)
                    bf[n][kk] = ldsB(cur, n, kk);
#pragma unroll
            for (int mm = 0; mm < 2; ++mm)
#pragma unroll
                for (int kk = 0; kk < 2; ++kk)
                    af[mm][kk] = ldsA(cur, mm, kk);
            __builtin_amdgcn_s_barrier();
            asm volatile("s_waitcnt lgkmcnt(0)" ::: "memory");
            __builtin_amdgcn_s_setprio(1);
#pragma unroll
            for (int mm = 0; mm < 2; ++mm)
#pragma unroll
                for (int n = 0; n < 4; ++n)
#pragma unroll
                    for (int kk = 0; kk < 2; ++kk)
                        acc[mm][n] = __builtin_amdgcn_mfma_f32_16x16x32_bf16(
                            af[mm][kk], bf[n][kk], acc[mm][n], 0, 0, 0);
            __builtin_amdgcn_s_setprio(0);

            // ---- ph1: stage B1(u+1); read A m23; vmcnt(4); MFMA m23 ----
            STAGE(1, 1, u + 1);
#pragma unroll
            for (int mm = 0; mm < 2; ++mm)
#pragma unroll
                for (int kk = 0; kk < 2; ++kk)
                    af[mm][kk] = ldsA(cur, 2 + mm, kk);
            asm volatile("s_waitcnt vmcnt(4)" ::: "memory");
            __builtin_amdgcn_s_barrier();
            asm volatile("s_waitcnt lgkmcnt(0)" ::: "memory");
            __builtin_amdgcn_s_setprio(1);
#pragma unroll
            for (int mm = 0; mm < 2; ++mm)
#pragma unroll
                for (int n = 0; n < 4; ++n)
#pragma unroll
                    for (int kk = 0; kk < 2; ++kk)
                        acc[2 + mm][n] = __builtin_amdgcn_mfma_f32_16x16x32_bf16(
                            af[mm][kk], bf[n][kk], acc[2 + mm][n], 0, 0, 0);
            __builtin_amdgcn_s_setprio(0);

            // ---- ph2: stage A0(u+1); read A m45; MFMA m45 ----
            STAGE(0, 0, u + 1);
#pragma unroll
            for (int mm = 0; mm < 2; ++mm)
#pragma unroll
                for (int kk = 0; kk < 2; ++kk)
                    af[mm][kk] = ldsA(cur, 4 + mm, kk);
            __builtin_amdgcn_s_barrier();
            asm volatile("s_waitcnt lgkmcnt(0)" ::: "memory");
            __builtin_amdgcn_s_setprio(1);
#pragma unroll
            for (int mm = 0; mm < 2; ++mm)
#pragma unroll
                for (int n = 0; n < 4; ++n)
#pragma unroll
                    for (int kk = 0; kk < 2; ++kk)
                        acc[4 + mm][n] = __builtin_amdgcn_mfma_f32_16x16x32_bf16(
                            af[mm][kk], bf[n][kk], acc[4 + mm][n], 0, 0, 0);
            __builtin_amdgcn_s_setprio(0);

            // ---- ph3: stage A1(u+1); read A m67; vmcnt(2); MFMA m67 ----
            STAGE(0, 1, u + 1);
#pragma unroll
            for (int mm = 0; mm < 2; ++mm)
#pragma unroll
                for (int kk = 0; kk < 2; ++kk)
                    af[mm][kk] = ldsA(cur, 6 + mm, kk);
            asm volatile("s_waitcnt vmcnt(2)" ::: "memory");
            __builtin_amdgcn_s_barrier();
            asm volatile("s_waitcnt lgkmcnt(0)" ::: "memory");
            __builtin_amdgcn_s_setprio(1);
#pragma unroll
            for (int mm = 0; mm < 2; ++mm)
#pragma unroll
                for (int n = 0; n < 4; ++n)
#pragma unroll
                    for (int kk = 0; kk < 2; ++kk)
                        acc[6 + mm][n] = __builtin_amdgcn_mfma_f32_16x16x32_bf16(
                            af[mm][kk], bf[n][kk], acc[6 + mm][n], 0, 0, 0);
            __builtin_amdgcn_s_setprio(0);
        }

        // ---- per-tile epilogue (reg-only, no LDS; runs inside ph3's region) ----
        const int g = g0 + ti;
        const size_t rowBase = (size_t)(g >> LG_TN) << 8;
        const size_t colBase = (size_t)(g & ((1 << LG_TN) - 1)) << 8;
        const int orow = (lane >> 4) * 4;
        const int ocol = lane & 15;
#pragma unroll
        for (int m = 0; m < 8; ++m) {
            const size_t rb = rowBase + (size_t)((m >> 1) * 64 + wr * 32 + (m & 1) * 16 + orow);
#pragma unroll
            for (int n = 0; n < 4; ++n) {
                const size_t col = colBase + (size_t)(wc * 64 + n * 16 + ocol);
                const float bv = bias[col];
#pragma unroll
                for (int j = 0; j < 4; ++j) {
                    float v = acc[m][n][j] + bv;
                    if constexpr (GELU_OUT) {
                        ((bf16_t*)Cout)[(rb + j) * (size_t)NDIM + col] = (bf16_t)fast_gelu(v);
                    } else {
                        ((float*)Cout)[(rb + j) * (size_t)NDIM + col] = v;
                    }
                }
                acc[m][n] = (f32x4){0.f, 0.f, 0.f, 0.f};
            }
        }
    }
    asm volatile("s_waitcnt vmcnt(0)" ::: "memory");   // drain tail dummy loads
}

// ---------------------------------------------------------------------------
extern "C" void kernel_launch(void* const* d_in, const int* in_sizes, int n_in,
                              void* d_out, int out_size, void* d_ws, size_t ws_size,
                              hipStream_t stream) {
    const float* x  = (const float*)d_in[0];  // [16384, 2048]
    const float* p1 = (const float*)d_in[1];  // [8192, 2048]
    const float* b1 = (const float*)d_in[2];  // [8192]
    const float* p2 = (const float*)d_in[3];  // [2048, 8192]
    const float* b2 = (const float*)d_in[4];  // [2048]
    // d_in[5] = gate_w, unused (routing is identity on the output)
    float* out = (float*)d_out;

    char* ws = (char*)d_ws;
    bf16_t* xb  = (bf16_t*)(ws);                          // 64 MB
    bf16_t* p1b = (bf16_t*)(ws + ((size_t)64 << 20));     // 32 MB
    bf16_t* p2b = (bf16_t*)(ws + ((size_t)96 << 20));     // 32 MB
    bf16_t* h   = (bf16_t*)(ws + ((size_t)128 << 20));    // 256 MB

    // GEMM1: [T,E] x [H,E]^T -> h.  2048 tiles = 256 blocks x 8 tiles.
    auto g1 = gemm256<true, 5, 5, 3, E_DIM, H_DIM>;
    // GEMM2: [T,H] x [E,H]^T -> out. 512 tiles = 256 blocks x 2 tiles.
    auto g2 = gemm256<false, 7, 3, 1, H_DIM, E_DIM>;

    (void)hipFuncSetAttribute((const void*)g1,
                              hipFuncAttributeMaxDynamicSharedMemorySize, 131072);
    (void)hipFuncSetAttribute((const void*)g2,
                              hipFuncAttributeMaxDynamicSharedMemorySize, 131072);

    cvt_f32_bf16<<<2048, 256, 0, stream>>>(x,  xb,  (T_DIM * E_DIM) / 4);
    cvt_f32_bf16<<<1024, 256, 0, stream>>>(p1, p1b, (H_DIM * E_DIM) / 4);
    cvt_f32_bf16<<<1024, 256, 0, stream>>>(p2, p2b, (E_DIM * H_DIM) / 4);

    g1<<<256, 512, 131072, stream>>>(xb, p1b, b1, (void*)h);
    g2<<<256, 512, 131072, stream>>>(h, p2b, b2, (void*)out);
}